// Round 1
// baseline (697.883 us; speedup 1.0000x reference)
//
#include <hip/hip_runtime.h>

#define NN 10000
#define DIN 128
#define HD 64
#define HH 128          // H*HEADS
#define NE 250000
#define NP 100000
#define P1_BLOCKS 2500
#define PART_STRIDE 4096

// ---------------- CSR build ----------------

__global__ void count_kernel(const int* e12, const int* e21, int* cnt12, int* cnt21) {
    int t = blockIdx.x * blockDim.x + threadIdx.x;
    if (t < NE)            atomicAdd(&cnt12[e12[NE + t]], 1);
    else if (t < 2 * NE)   atomicAdd(&cnt21[e21[NE + (t - NE)]], 1);
}

__global__ void scan_kernel(const int* cnt12, const int* cnt21,
                            int* ptr12, int* ptr21, int* cur12, int* cur21) {
    const int* cnt = blockIdx.x ? cnt21 : cnt12;
    int* ptr = blockIdx.x ? ptr21 : ptr12;
    int* cur = blockIdx.x ? cur21 : cur12;
    const int T = 1024, C = 10;                 // 1024*10 = 10240 >= 10000
    __shared__ int sm[1024];
    int t = threadIdx.x;
    int v[C]; int tot = 0;
    int base = t * C;
    #pragma unroll
    for (int i = 0; i < C; i++) {
        int id = base + i;
        v[i] = (id < NN) ? cnt[id] : 0;
        tot += v[i];
    }
    sm[t] = tot; __syncthreads();
    for (int off = 1; off < T; off <<= 1) {
        int x = (t >= off) ? sm[t - off] : 0;
        __syncthreads();
        sm[t] += x;
        __syncthreads();
    }
    int run = sm[t] - tot;                      // exclusive prefix
    #pragma unroll
    for (int i = 0; i < C; i++) {
        int id = base + i;
        if (id < NN) { ptr[id] = run; cur[id] = run; }
        run += v[i];
    }
    if (t == T - 1) ptr[NN] = run;
}

__global__ void fill_kernel(const int* e12, const int* e21,
                            int* cur12, int* cur21, int* idx12, int* idx21) {
    int t = blockIdx.x * blockDim.x + threadIdx.x;
    if (t < NE) {
        int c = e12[NE + t];
        int p = atomicAdd(&cur12[c], 1);
        idx12[p] = t;
    } else if (t < 2 * NE) {
        int e = t - NE;
        int c = e21[NE + e];
        int p = atomicAdd(&cur21[c], 1);
        idx21[p] = e;
    }
}

// ---------------- GEMMs ----------------

// x = relu(xn @ Win[z] + b_in[z]); [10000,128]@[128,64]
__global__ void in_gemm(const float* xn1, const float* xn2,
                        const float* Win, const float* b_in,
                        float* x1, float* x2) {
    int z = blockIdx.z;
    const float* A = z ? xn2 : xn1;
    const float* W = Win + (size_t)z * DIN * HD;
    const float* b = b_in + (size_t)z * HD;
    float* O = z ? x2 : x1;
    __shared__ float As[8 * DIN];
    int tid = threadIdx.x;
    int row0 = blockIdx.x * 8;
    for (int i = tid; i < 8 * DIN; i += 256) As[i] = A[(size_t)row0 * DIN + i];
    __syncthreads();
    int c = tid & 63, rg = tid >> 6;            // rg 0..3, rows rg*2, rg*2+1
    float acc0 = b[c], acc1 = acc0;
    const float* a0 = &As[(rg * 2) * DIN];
    const float* a1 = &As[(rg * 2 + 1) * DIN];
    for (int k = 0; k < DIN; k++) {
        float w = W[k * HD + c];
        acc0 += a0[k] * w; acc1 += a1[k] * w;
    }
    acc0 = fmaxf(acc0, 0.f); acc1 = fmaxf(acc1, 0.f);
    int r = row0 + rg * 2;
    O[(size_t)r * HD + c] = acc0;
    O[(size_t)(r + 1) * HD + c] = acc1;
}

// K/Q/V = A @ W + b; [10000,64]@[64,128]; z: 0=K(src) 1=Q(dst) 2=V(src)
__global__ void kqv_gemm(const float* xsrc, const float* xdst,
                         const float* Wk, const float* Wq, const float* Wv,
                         const float* bk, const float* bq, const float* bv,
                         float* Kb, float* Qb, float* Vb) {
    int z = blockIdx.z;
    const float* A = (z == 1) ? xdst : xsrc;
    const float* W = (z == 0) ? Wk : (z == 1) ? Wq : Wv;
    const float* b = (z == 0) ? bk : (z == 1) ? bq : bv;
    float* O = (z == 0) ? Kb : (z == 1) ? Qb : Vb;
    __shared__ float As[8 * HD];
    int tid = threadIdx.x;
    int row0 = blockIdx.x * 8;
    for (int i = tid; i < 8 * HD; i += 256) As[i] = A[(size_t)row0 * HD + i];
    __syncthreads();
    int c = tid & 127, rg = tid >> 7;           // rg 0..1, 4 rows each
    float bb = b[c];
    float acc[4];
    #pragma unroll
    for (int i = 0; i < 4; i++) acc[i] = bb;
    for (int k = 0; k < HD; k++) {
        float w = W[k * HH + c];
        #pragma unroll
        for (int i = 0; i < 4; i++) acc[i] += As[(rg * 4 + i) * HD + k] * w;
    }
    #pragma unroll
    for (int i = 0; i < 4; i++)
        O[(size_t)(row0 + rg * 4 + i) * HH + c] = acc[i];
}

// x_new = agg @ Wout[l,z] + bout[l,z]; also writes into Em/Ed at col l*64
__global__ void out_gemm(const float* agg1, const float* agg2,
                         const float* Wout, const float* bout, int l,
                         float* x1, float* x2, float* Em, float* Ed) {
    int z = blockIdx.z;
    const float* A = z ? agg2 : agg1;
    const float* W = Wout + (size_t)(l * 2 + z) * HH * HD;
    const float* b = bout + (size_t)(l * 2 + z) * HD;
    float* X = z ? x2 : x1;
    float* EE = z ? Ed : Em;
    __shared__ float As[8 * HH];
    int tid = threadIdx.x;
    int row0 = blockIdx.x * 8;
    for (int i = tid; i < 8 * HH; i += 256) As[i] = A[(size_t)row0 * HH + i];
    __syncthreads();
    int c = tid & 63, rg = tid >> 6;
    float acc0 = b[c], acc1 = acc0;
    const float* a0 = &As[(rg * 2) * HH];
    const float* a1 = &As[(rg * 2 + 1) * HH];
    for (int k = 0; k < HH; k++) {
        float w = W[k * HD + c];
        acc0 += a0[k] * w; acc1 += a1[k] * w;
    }
    int r = row0 + rg * 2;
    X[(size_t)r * HD + c] = acc0;
    X[(size_t)(r + 1) * HD + c] = acc1;
    EE[(size_t)r * HH + l * HD + c] = acc0;
    EE[(size_t)(r + 1) * HH + l * HD + c] = acc1;
}

// ---------------- attention ----------------

// logits a[e,h] = leaky_relu(dot(K[row],Q[col])/8), per dest node via CSR;
// also block-partial sums of exp(a)
__global__ void logits_kernel(const int* ptr, const int* idx, const int* rows,
                              const float* Kb, const float* Qb,
                              float* alog, float* part) {
    int wave = threadIdx.x >> 6;
    int lane = threadIdx.x & 63;
    int c = blockIdx.x * 4 + wave;              // dest node, always < 10000
    float q0 = Qb[(size_t)c * HH + lane];
    float q1 = Qb[(size_t)c * HH + 64 + lane];
    float ex0 = 0.f, ex1 = 0.f;
    int jb = ptr[c], je = ptr[c + 1];
    for (int j = jb; j < je; j++) {
        int e = idx[j];
        int r = rows[e];
        float p0 = Kb[(size_t)r * HH + lane] * q0;
        float p1 = Kb[(size_t)r * HH + 64 + lane] * q1;
        #pragma unroll
        for (int off = 32; off; off >>= 1) {
            p0 += __shfl_xor(p0, off);
            p1 += __shfl_xor(p1, off);
        }
        float a0 = p0 * 0.125f; a0 = a0 > 0.f ? a0 : 0.2f * a0;
        float a1 = p1 * 0.125f; a1 = a1 > 0.f ? a1 : 0.2f * a1;
        if (lane == 0) {
            alog[2 * e] = a0; alog[2 * e + 1] = a1;
            ex0 += __expf(a0); ex1 += __expf(a1);
        }
    }
    __shared__ float sm[4][2];
    if (lane == 0) { sm[wave][0] = ex0; sm[wave][1] = ex1; }
    __syncthreads();
    if (threadIdx.x == 0) {
        part[blockIdx.x]               = sm[0][0] + sm[1][0] + sm[2][0] + sm[3][0];
        part[PART_STRIDE + blockIdx.x] = sm[0][1] + sm[1][1] + sm[2][1] + sm[3][1];
    }
}

__global__ void finalsum_kernel(const float* part, float* sbuf) {
    __shared__ float sm[256];
    int t = threadIdx.x;
    float s0 = 0.f, s1 = 0.f;
    for (int i = t; i < P1_BLOCKS; i += 256) {
        s0 += part[i];
        s1 += part[PART_STRIDE + i];
    }
    sm[t] = s0; __syncthreads();
    for (int off = 128; off; off >>= 1) { if (t < off) sm[t] += sm[t + off]; __syncthreads(); }
    if (t == 0) sbuf[0] = 1.f / sm[0];
    __syncthreads();
    sm[t] = s1; __syncthreads();
    for (int off = 128; off; off >>= 1) { if (t < off) sm[t] += sm[t + off]; __syncthreads(); }
    if (t == 0) sbuf[1] = 1.f / sm[0];
}

// agg[c] = (1/s) * sum_e exp(a[e]) * V[row_e]
__global__ void spmm_kernel(const int* ptr, const int* idx, const int* rows,
                            const float* alog, const float* Vb, const float* sbuf,
                            float* agg) {
    int wave = threadIdx.x >> 6;
    int lane = threadIdx.x & 63;
    int c = blockIdx.x * 4 + wave;
    float inv0 = sbuf[0], inv1 = sbuf[1];
    float acc0 = 0.f, acc1 = 0.f;
    int jb = ptr[c], je = ptr[c + 1];
    for (int j = jb; j < je; j++) {
        int e = idx[j];
        int r = rows[e];
        float a0 = alog[2 * e], a1 = alog[2 * e + 1];
        float e0 = __expf(a0), e1 = __expf(a1);
        acc0 += e0 * Vb[(size_t)r * HH + lane];
        acc1 += e1 * Vb[(size_t)r * HH + 64 + lane];
    }
    agg[(size_t)c * HH + lane] = acc0 * inv0;
    agg[(size_t)c * HH + 64 + lane] = acc1 * inv1;
}

// ---------------- prediction ----------------

__global__ void pred_kernel(const float* Em, const float* Ed, const int* pe, float* out) {
    int wg = (blockIdx.x * blockDim.x + threadIdx.x) >> 6;
    int lane = threadIdx.x & 63;
    if (wg >= NP) return;
    int m = pe[wg], d = pe[NP + wg];
    float p = Em[(size_t)m * HH + lane] * Ed[(size_t)d * HH + lane]
            + Em[(size_t)m * HH + 64 + lane] * Ed[(size_t)d * HH + 64 + lane];
    #pragma unroll
    for (int off = 32; off; off >>= 1) p += __shfl_xor(p, off);
    if (lane == 0) out[wg] = p;
}

// ---------------- host ----------------

extern "C" void kernel_launch(void* const* d_in, const int* in_sizes, int n_in,
                              void* d_out, int out_size, void* d_ws, size_t ws_size,
                              hipStream_t stream) {
    (void)in_sizes; (void)n_in; (void)out_size; (void)ws_size;
    const float* x_n1 = (const float*)d_in[0];
    const float* x_n2 = (const float*)d_in[1];
    const int*   e12  = (const int*)d_in[2];
    const int*   e21  = (const int*)d_in[3];
    const int*   pe   = (const int*)d_in[4];
    const float* Win  = (const float*)d_in[5];
    const float* b_in = (const float*)d_in[6];
    const float* Wk   = (const float*)d_in[7];
    const float* bk   = (const float*)d_in[8];
    const float* Wq   = (const float*)d_in[9];
    const float* bq   = (const float*)d_in[10];
    const float* Wv   = (const float*)d_in[11];
    const float* bv   = (const float*)d_in[12];
    const float* Wout = (const float*)d_in[13];
    const float* bout = (const float*)d_in[14];
    float* out = (float*)d_out;

    char* w = (char*)d_ws;
    auto carve = [&](size_t nbytes) -> void* {
        void* p = (void*)w;
        w += (nbytes + 255) & ~(size_t)255;
        return p;
    };
    float* x1   = (float*)carve((size_t)NN * HD * 4);
    float* x2   = (float*)carve((size_t)NN * HD * 4);
    float* Kb   = (float*)carve((size_t)NN * HH * 4);
    float* Qb   = (float*)carve((size_t)NN * HH * 4);
    float* Vb   = (float*)carve((size_t)NN * HH * 4);
    float* agg1 = (float*)carve((size_t)NN * HH * 4);
    float* agg2 = (float*)carve((size_t)NN * HH * 4);
    float* Em   = (float*)carve((size_t)NN * HH * 4);
    float* Ed   = (float*)carve((size_t)NN * HH * 4);
    float* alog = (float*)carve((size_t)NE * 2 * 4);
    float* part = (float*)carve((size_t)2 * PART_STRIDE * 4);
    float* sbuf = (float*)carve(256);
    int* cnt    = (int*)carve((size_t)2 * NN * 4);   // cnt12 | cnt21 contiguous
    int* cur12  = (int*)carve((size_t)NN * 4);
    int* cur21  = (int*)carve((size_t)NN * 4);
    int* ptr12  = (int*)carve((size_t)(NN + 1) * 4);
    int* ptr21  = (int*)carve((size_t)(NN + 1) * 4);
    int* idx12  = (int*)carve((size_t)NE * 4);
    int* idx21  = (int*)carve((size_t)NE * 4);
    int* cnt12 = cnt;
    int* cnt21 = cnt + NN;

    // CSR build (structure reused across layers)
    hipMemsetAsync(cnt, 0, (size_t)2 * NN * 4, stream);
    int eb = (2 * NE + 255) / 256;
    count_kernel<<<eb, 256, 0, stream>>>(e12, e21, cnt12, cnt21);
    scan_kernel<<<2, 1024, 0, stream>>>(cnt12, cnt21, ptr12, ptr21, cur12, cur21);
    fill_kernel<<<eb, 256, 0, stream>>>(e12, e21, cur12, cur21, idx12, idx21);

    // input linears + relu
    in_gemm<<<dim3(NN / 8, 1, 2), 256, 0, stream>>>(x_n1, x_n2, Win, b_in, x1, x2);

    for (int l = 0; l < 2; l++) {
        for (int rel = 0; rel < 2; rel++) {
            const float* xsrc = rel == 0 ? x1 : x2;
            const float* xdst = rel == 0 ? x2 : x1;
            const int* ep  = rel == 0 ? ptr12 : ptr21;
            const int* ei  = rel == 0 ? idx12 : idx21;
            const int* er  = rel == 0 ? e12 : e21;     // rows at [0..NE)
            float* agg     = rel == 0 ? agg2 : agg1;
            size_t wo = (size_t)(l * 2 + rel) * HD * HH;
            size_t bo = (size_t)(l * 2 + rel) * HH;
            kqv_gemm<<<dim3(NN / 8, 1, 3), 256, 0, stream>>>(
                xsrc, xdst, Wk + wo, Wq + wo, Wv + wo, bk + bo, bq + bo, bv + bo,
                Kb, Qb, Vb);
            logits_kernel<<<P1_BLOCKS, 256, 0, stream>>>(ep, ei, er, Kb, Qb, alog, part);
            finalsum_kernel<<<1, 256, 0, stream>>>(part, sbuf);
            spmm_kernel<<<P1_BLOCKS, 256, 0, stream>>>(ep, ei, er, alog, Vb, sbuf, agg);
        }
        out_gemm<<<dim3(NN / 8, 1, 2), 256, 0, stream>>>(
            agg1, agg2, Wout, bout, l, x1, x2, Em, Ed);
    }

    pred_kernel<<<(NP * 64) / 256, 256, 0, stream>>>(Em, Ed, pe, out);
}

// Round 2
// 426.632 us; speedup vs baseline: 1.6358x; 1.6358x over previous
//
#include <hip/hip_runtime.h>

#define NN 10000
#define DIN 128
#define HD 64
#define HH 128          // H*HEADS
#define NE 250000
#define NP 100000
#define P1_BLOCKS 2500
#define PART_STRIDE 4096

// ---------------- CSR build ----------------

__global__ void count_kernel(const int* e12, const int* e21, int* cnt12, int* cnt21) {
    int t = blockIdx.x * blockDim.x + threadIdx.x;
    if (t < NE)            atomicAdd(&cnt12[e12[NE + t]], 1);
    else if (t < 2 * NE)   atomicAdd(&cnt21[e21[NE + (t - NE)]], 1);
}

__global__ void scan_kernel(const int* cnt12, const int* cnt21,
                            int* ptr12, int* ptr21, int* cur12, int* cur21) {
    const int* cnt = blockIdx.x ? cnt21 : cnt12;
    int* ptr = blockIdx.x ? ptr21 : ptr12;
    int* cur = blockIdx.x ? cur21 : cur12;
    const int T = 1024, C = 10;                 // 1024*10 = 10240 >= 10000
    __shared__ int sm[1024];
    int t = threadIdx.x;
    int v[C]; int tot = 0;
    int base = t * C;
    #pragma unroll
    for (int i = 0; i < C; i++) {
        int id = base + i;
        v[i] = (id < NN) ? cnt[id] : 0;
        tot += v[i];
    }
    sm[t] = tot; __syncthreads();
    for (int off = 1; off < T; off <<= 1) {
        int x = (t >= off) ? sm[t - off] : 0;
        __syncthreads();
        sm[t] += x;
        __syncthreads();
    }
    int run = sm[t] - tot;                      // exclusive prefix
    #pragma unroll
    for (int i = 0; i < C; i++) {
        int id = base + i;
        if (id < NN) { ptr[id] = run; cur[id] = run; }
        run += v[i];
    }
    if (t == T - 1) ptr[NN] = run;
}

// writes rows_sorted directly: no idx indirection in the hot loops
__global__ void fill_kernel(const int* e12, const int* e21,
                            int* cur12, int* cur21, int* rs12, int* rs21) {
    int t = blockIdx.x * blockDim.x + threadIdx.x;
    if (t < NE) {
        int c = e12[NE + t];
        int p = atomicAdd(&cur12[c], 1);
        rs12[p] = e12[t];
    } else if (t < 2 * NE) {
        int e = t - NE;
        int c = e21[NE + e];
        int p = atomicAdd(&cur21[c], 1);
        rs21[p] = e21[e];
    }
}

// ---------------- GEMMs ----------------

// x = relu(xn @ Win[z] + b_in[z]); [10000,128]@[128,64]
// block: 16 rows x 64 cols; thread = (row, colgroup of 4)
__global__ void in_gemm(const float* xn1, const float* xn2,
                        const float* Win, const float* b_in,
                        float* x1, float* x2) {
    int z = blockIdx.z;
    const float4* A4 = (const float4*)(z ? xn2 : xn1);
    const float4* W4 = (const float4*)(Win + (size_t)z * DIN * HD);
    const float4* b4 = (const float4*)(b_in + (size_t)z * HD);
    float4* O4 = (float4*)(z ? x2 : x1);
    __shared__ float As[16 * DIN];
    int tid = threadIdx.x;
    int row0 = blockIdx.x * 16;
    float4* As4 = (float4*)As;
    As4[tid]       = A4[(size_t)row0 * 32 + tid];
    As4[tid + 256] = A4[(size_t)row0 * 32 + tid + 256];
    __syncthreads();
    int r = tid >> 4, cg = tid & 15;
    float4 acc = b4[cg];
    const float* a = &As[r * DIN];
    for (int k = 0; k < DIN; k++) {
        float av = a[k];
        float4 w = W4[k * 16 + cg];
        acc.x += av * w.x; acc.y += av * w.y; acc.z += av * w.z; acc.w += av * w.w;
    }
    acc.x = fmaxf(acc.x, 0.f); acc.y = fmaxf(acc.y, 0.f);
    acc.z = fmaxf(acc.z, 0.f); acc.w = fmaxf(acc.w, 0.f);
    O4[(size_t)(row0 + r) * 16 + cg] = acc;
}

// K/Q/V = A @ W + b; [10000,64]@[64,128]; z: 0=K(src) 1=Q(dst) 2=V(src)
// block: 8 rows x 128 cols
__global__ void kqv_gemm(const float* xsrc, const float* xdst,
                         const float* Wk, const float* Wq, const float* Wv,
                         const float* bk, const float* bq, const float* bv,
                         float* Kb, float* Qb, float* Vb) {
    int z = blockIdx.z;
    const float* A = (z == 1) ? xdst : xsrc;
    const float* W = (z == 0) ? Wk : (z == 1) ? Wq : Wv;
    const float* b = (z == 0) ? bk : (z == 1) ? bq : bv;
    float* O = (z == 0) ? Kb : (z == 1) ? Qb : Vb;
    const float4* A4 = (const float4*)A;
    const float4* W4 = (const float4*)W;
    const float4* b4 = (const float4*)b;
    float4* O4 = (float4*)O;
    __shared__ float As[8 * HD];
    int tid = threadIdx.x;
    int row0 = blockIdx.x * 8;
    if (tid < 128) ((float4*)As)[tid] = A4[(size_t)row0 * 16 + tid];
    __syncthreads();
    int r = tid >> 5, cg = tid & 31;
    float4 acc = b4[cg];
    const float* a = &As[r * HD];
    for (int k = 0; k < HD; k++) {
        float av = a[k];
        float4 w = W4[k * 32 + cg];
        acc.x += av * w.x; acc.y += av * w.y; acc.z += av * w.z; acc.w += av * w.w;
    }
    O4[(size_t)(row0 + r) * 32 + cg] = acc;
}

// x_new = (agg * softmax_scale) @ Wout + bout; scale folded into LDS staging.
// block: 16 rows x 64 cols
__global__ void out_gemm(const float* agg1, const float* agg2,
                         const float* Wout, const float* bout, int l,
                         const float* sbuf,
                         float* x1, float* x2, float* Em, float* Ed) {
    int z = blockIdx.z;
    const float4* A4 = (const float4*)(z ? agg2 : agg1);
    const float4* W4 = (const float4*)(Wout + (size_t)(l * 2 + z) * HH * HD);
    const float4* b4 = (const float4*)(bout + (size_t)(l * 2 + z) * HD);
    float inv0 = sbuf[z ? 0 : 2];   // z=0 -> agg1 (rel 21, slots 2,3); z=1 -> agg2 (rel 12, slots 0,1)
    float inv1 = sbuf[z ? 1 : 3];
    float4* X4 = (float4*)(z ? x2 : x1);
    float4* E4 = (float4*)(z ? Ed : Em);
    __shared__ float As[16 * HH];
    int tid = threadIdx.x;
    int row0 = blockIdx.x * 16;
    float4* As4 = (float4*)As;
    {
        float4 t0 = A4[(size_t)row0 * 32 + tid];
        float4 t1 = A4[(size_t)row0 * 32 + tid + 256];
        float s0 = ((tid & 31) < 16) ? inv0 : inv1;          // cols 0-63 head0
        float s1 = (((tid + 256) & 31) < 16) ? inv0 : inv1;
        t0.x *= s0; t0.y *= s0; t0.z *= s0; t0.w *= s0;
        t1.x *= s1; t1.y *= s1; t1.z *= s1; t1.w *= s1;
        As4[tid] = t0; As4[tid + 256] = t1;
    }
    __syncthreads();
    int r = tid >> 4, cg = tid & 15;
    float4 acc = b4[cg];
    const float* a = &As[r * HH];
    for (int k = 0; k < HH; k++) {
        float av = a[k];
        float4 w = W4[k * 16 + cg];
        acc.x += av * w.x; acc.y += av * w.y; acc.z += av * w.z; acc.w += av * w.w;
    }
    X4[(size_t)(row0 + r) * 16 + cg] = acc;
    E4[(size_t)(row0 + r) * 32 + l * 16 + cg] = acc;
}

// ---------------- fused attention conv (logits + exp + weighted scatter) ----------------
// wave per dest node; 4 edges in flight (16 lanes each); unnormalized acc + exp-sums
__global__ void conv_kernel(const int* ptr, const int* rows,
                            const float* Kb, const float* Qb, const float* Vb,
                            float* agg, float* part) {
    const float4* K4 = (const float4*)Kb;
    const float4* Q4 = (const float4*)Qb;
    const float4* V4 = (const float4*)Vb;
    float4* A4 = (float4*)agg;
    int wave = threadIdx.x >> 6, lane = threadIdx.x & 63;
    int g = lane >> 4, s = lane & 15;
    int c = blockIdx.x * 4 + wave;
    float4 q0 = Q4[(size_t)c * 32 + s];
    float4 q1 = Q4[(size_t)c * 32 + 16 + s];
    float4 acc0 = {0.f, 0.f, 0.f, 0.f}, acc1 = {0.f, 0.f, 0.f, 0.f};
    float ex0 = 0.f, ex1 = 0.f;
    int jb = ptr[c], je = ptr[c + 1];
    int jg = jb + g;
    int r = (jg < je) ? rows[jg] : -1;           // prefetched row index
    for (int j = jb; j < je; j += 4) {
        int jn = j + 4 + g;
        int rn = (jn < je) ? rows[jn] : -1;
        int rr = (r >= 0) ? r : 0;
        float4 k0 = K4[(size_t)rr * 32 + s];
        float4 k1 = K4[(size_t)rr * 32 + 16 + s];
        float4 v0 = V4[(size_t)rr * 32 + s];
        float4 v1 = V4[(size_t)rr * 32 + 16 + s];
        float p0 = k0.x * q0.x + k0.y * q0.y + k0.z * q0.z + k0.w * q0.w;
        float p1 = k1.x * q1.x + k1.y * q1.y + k1.z * q1.z + k1.w * q1.w;
        #pragma unroll
        for (int off = 1; off <= 8; off <<= 1) {
            p0 += __shfl_xor(p0, off);
            p1 += __shfl_xor(p1, off);
        }
        p0 *= 0.125f; p1 *= 0.125f;
        p0 = p0 > 0.f ? p0 : 0.2f * p0;
        p1 = p1 > 0.f ? p1 : 0.2f * p1;
        float e0 = (r >= 0) ? __expf(p0) : 0.f;
        float e1 = (r >= 0) ? __expf(p1) : 0.f;
        acc0.x += e0 * v0.x; acc0.y += e0 * v0.y; acc0.z += e0 * v0.z; acc0.w += e0 * v0.w;
        acc1.x += e1 * v1.x; acc1.y += e1 * v1.y; acc1.z += e1 * v1.z; acc1.w += e1 * v1.w;
        if (s == 0) { ex0 += e0; ex1 += e1; }
        r = rn;
    }
    // cross-group reduce of the 8 partial accumulators (groups hold disjoint edge subsets)
    #pragma unroll
    for (int off = 16; off <= 32; off <<= 1) {
        acc0.x += __shfl_xor(acc0.x, off); acc0.y += __shfl_xor(acc0.y, off);
        acc0.z += __shfl_xor(acc0.z, off); acc0.w += __shfl_xor(acc0.w, off);
        acc1.x += __shfl_xor(acc1.x, off); acc1.y += __shfl_xor(acc1.y, off);
        acc1.z += __shfl_xor(acc1.z, off); acc1.w += __shfl_xor(acc1.w, off);
    }
    if (g == 0) {
        A4[(size_t)c * 32 + s] = acc0;
        A4[(size_t)c * 32 + 16 + s] = acc1;
    }
    float z0 = (s == 0) ? ex0 : 0.f;
    float z1 = (s == 0) ? ex1 : 0.f;
    z0 += __shfl_xor(z0, 16); z0 += __shfl_xor(z0, 32);
    z1 += __shfl_xor(z1, 16); z1 += __shfl_xor(z1, 32);
    __shared__ float sm[4][2];
    if (lane == 0) { sm[wave][0] = z0; sm[wave][1] = z1; }
    __syncthreads();
    if (threadIdx.x == 0) {
        part[blockIdx.x]               = sm[0][0] + sm[1][0] + sm[2][0] + sm[3][0];
        part[PART_STRIDE + blockIdx.x] = sm[0][1] + sm[1][1] + sm[2][1] + sm[3][1];
    }
}

__global__ void finalsum_kernel(const float* part, float* sbuf2) {
    __shared__ float sm[256];
    int t = threadIdx.x;
    float s0 = 0.f, s1 = 0.f;
    for (int i = t; i < P1_BLOCKS; i += 256) {
        s0 += part[i];
        s1 += part[PART_STRIDE + i];
    }
    sm[t] = s0; __syncthreads();
    for (int off = 128; off; off >>= 1) { if (t < off) sm[t] += sm[t + off]; __syncthreads(); }
    if (t == 0) sbuf2[0] = 1.f / sm[0];
    __syncthreads();
    sm[t] = s1; __syncthreads();
    for (int off = 128; off; off >>= 1) { if (t < off) sm[t] += sm[t + off]; __syncthreads(); }
    if (t == 0) sbuf2[1] = 1.f / sm[0];
}

// ---------------- prediction ----------------
// 16 lanes per pair, float4 loads
__global__ void pred_kernel(const float* Em, const float* Ed, const int* pe, float* out) {
    const float4* Em4 = (const float4*)Em;
    const float4* Ed4 = (const float4*)Ed;
    int pair = blockIdx.x * 16 + (threadIdx.x >> 4);
    int s = threadIdx.x & 15;
    int m = pe[pair], d = pe[NP + pair];
    float4 a0 = Em4[(size_t)m * 32 + s];
    float4 a1 = Em4[(size_t)m * 32 + 16 + s];
    float4 b0 = Ed4[(size_t)d * 32 + s];
    float4 b1 = Ed4[(size_t)d * 32 + 16 + s];
    float p = a0.x * b0.x + a0.y * b0.y + a0.z * b0.z + a0.w * b0.w
            + a1.x * b1.x + a1.y * b1.y + a1.z * b1.z + a1.w * b1.w;
    #pragma unroll
    for (int off = 1; off <= 8; off <<= 1) p += __shfl_xor(p, off);
    if (s == 0) out[pair] = p;
}

// ---------------- host ----------------

extern "C" void kernel_launch(void* const* d_in, const int* in_sizes, int n_in,
                              void* d_out, int out_size, void* d_ws, size_t ws_size,
                              hipStream_t stream) {
    (void)in_sizes; (void)n_in; (void)out_size; (void)ws_size;
    const float* x_n1 = (const float*)d_in[0];
    const float* x_n2 = (const float*)d_in[1];
    const int*   e12  = (const int*)d_in[2];
    const int*   e21  = (const int*)d_in[3];
    const int*   pe   = (const int*)d_in[4];
    const float* Win  = (const float*)d_in[5];
    const float* b_in = (const float*)d_in[6];
    const float* Wk   = (const float*)d_in[7];
    const float* bk   = (const float*)d_in[8];
    const float* Wq   = (const float*)d_in[9];
    const float* bq   = (const float*)d_in[10];
    const float* Wv   = (const float*)d_in[11];
    const float* bv   = (const float*)d_in[12];
    const float* Wout = (const float*)d_in[13];
    const float* bout = (const float*)d_in[14];
    float* out = (float*)d_out;

    char* w = (char*)d_ws;
    auto carve = [&](size_t nbytes) -> void* {
        void* p = (void*)w;
        w += (nbytes + 255) & ~(size_t)255;
        return p;
    };
    float* x1   = (float*)carve((size_t)NN * HD * 4);
    float* x2   = (float*)carve((size_t)NN * HD * 4);
    float* Kb   = (float*)carve((size_t)NN * HH * 4);
    float* Qb   = (float*)carve((size_t)NN * HH * 4);
    float* Vb   = (float*)carve((size_t)NN * HH * 4);
    float* agg1 = (float*)carve((size_t)NN * HH * 4);
    float* agg2 = (float*)carve((size_t)NN * HH * 4);
    float* Em   = (float*)carve((size_t)NN * HH * 4);
    float* Ed   = (float*)carve((size_t)NN * HH * 4);
    float* part = (float*)carve((size_t)2 * PART_STRIDE * 4);
    float* sbuf = (float*)carve(256);
    int* cnt    = (int*)carve((size_t)2 * NN * 4);
    int* cur12  = (int*)carve((size_t)NN * 4);
    int* cur21  = (int*)carve((size_t)NN * 4);
    int* ptr12  = (int*)carve((size_t)(NN + 1) * 4);
    int* ptr21  = (int*)carve((size_t)(NN + 1) * 4);
    int* rs12   = (int*)carve((size_t)NE * 4);
    int* rs21   = (int*)carve((size_t)NE * 4);
    int* cnt12 = cnt;
    int* cnt21 = cnt + NN;

    // CSR build
    hipMemsetAsync(cnt, 0, (size_t)2 * NN * 4, stream);
    int eb = (2 * NE + 255) / 256;
    count_kernel<<<eb, 256, 0, stream>>>(e12, e21, cnt12, cnt21);
    scan_kernel<<<2, 1024, 0, stream>>>(cnt12, cnt21, ptr12, ptr21, cur12, cur21);
    fill_kernel<<<eb, 256, 0, stream>>>(e12, e21, cur12, cur21, rs12, rs21);

    // input linears + relu
    in_gemm<<<dim3(NN / 16, 1, 2), 256, 0, stream>>>(x_n1, x_n2, Win, b_in, x1, x2);

    for (int l = 0; l < 2; l++) {
        for (int rel = 0; rel < 2; rel++) {
            const float* xsrc = rel == 0 ? x1 : x2;
            const float* xdst = rel == 0 ? x2 : x1;
            const int* ep  = rel == 0 ? ptr12 : ptr21;
            const int* rs  = rel == 0 ? rs12 : rs21;
            float* agg     = rel == 0 ? agg2 : agg1;
            size_t wo = (size_t)(l * 2 + rel) * HD * HH;
            size_t bo = (size_t)(l * 2 + rel) * HH;
            kqv_gemm<<<dim3(NN / 8, 1, 3), 256, 0, stream>>>(
                xsrc, xdst, Wk + wo, Wq + wo, Wv + wo, bk + bo, bq + bo, bv + bo,
                Kb, Qb, Vb);
            conv_kernel<<<P1_BLOCKS, 256, 0, stream>>>(ep, rs, Kb, Qb, Vb, agg, part);
            finalsum_kernel<<<1, 256, 0, stream>>>(part, sbuf + rel * 2);
        }
        out_gemm<<<dim3(NN / 16, 1, 2), 256, 0, stream>>>(
            agg1, agg2, Wout, bout, l, sbuf, x1, x2, Em, Ed);
    }

    pred_kernel<<<NP / 16, 256, 0, stream>>>(Em, Ed, pe, out);
}